// Round 1
// baseline (273.221 us; speedup 1.0000x reference)
//
#include <hip/hip_runtime.h>
#include <stdint.h>

#define B_ 4
#define C_ 256
#define H_ 64
#define W_ 64
#define O_ 256
#define K_ 9
#define CK 2304     // K_*C_  (ck = k*256 + c, k-major)
#define HW 4096
#define NTOT 16384  // B_*HW

typedef __bf16 bf16x8 __attribute__((ext_vector_type(8)));
typedef float f32x4 __attribute__((ext_vector_type(4)));

__device__ __forceinline__ uint16_t f2bf(float f) {
  uint32_t u = __builtin_bit_cast(uint32_t, f);
  return (uint16_t)((u + 0x7FFFu + ((u >> 16) & 1u)) >> 16);
}

// ---------------- K0: weight fp32 [O][C][3][3] -> bf16 wb[O][k*256+c] ----------------
__global__ void k0_wconv(const float* __restrict__ weight, uint16_t* __restrict__ wb) {
  int idx = blockIdx.x * 256 + threadIdx.x;
  if (idx >= O_ * CK) return;
  int o = idx / CK;
  int rem = idx - o * CK;
  int k = rem >> 8;
  int c = rem & 255;
  wb[idx] = f2bf(weight[(o * C_ + c) * K_ + k]);
}

// ---------------- K1: offset conv (fp32) -> py/px/mask [b][k][h][w] ----------------
// block = (b, h, jq) ; jq in 0..6 covers j = jq*4 .. jq*4+3 (27 channels total)
// threads: w = t&63, cs = t>>6 splits C into 4 chunks; LDS reduction at end.
__global__ void k1_offconv(const float* __restrict__ x, const float* __restrict__ w_om,
                           const float* __restrict__ b_om, float* __restrict__ pypxmk) {
  int bx = blockIdx.x;
  int jq = bx % 7;
  int h = (bx / 7) % H_;
  int b = bx / (7 * H_);
  int t = threadIdx.x;
  int w = t & 63;
  int cs = __builtin_amdgcn_readfirstlane(t >> 6);

  float acc[4] = {0.f, 0.f, 0.f, 0.f};
  const float* xb = x + (b * C_) * HW;

  for (int ci = 0; ci < 64; ++ci) {
    int c = cs * 64 + ci;
    const float* xr = xb + c * HW;
    float xv[3][3];
#pragma unroll
    for (int r = 0; r < 3; ++r) {
      int y = h - 1 + r;
      bool yv = ((unsigned)y < 64u);
#pragma unroll
      for (int dx = 0; dx < 3; ++dx) {
        int xx = w - 1 + dx;
        bool v = yv && ((unsigned)xx < 64u);
        xv[r][dx] = v ? xr[y * 64 + xx] : 0.f;
      }
    }
    const float* wp = w_om + ((jq * 4) * C_ + c) * 9;
#pragma unroll
    for (int jj = 0; jj < 4; ++jj) {
      int j = jq * 4 + jj;
      int jeff = (j < 27) ? jj : 0;  // jq=6,jj=3 is dead; avoid OOB read
      const float* wj = wp + jeff * (C_ * 9);
      float a = 0.f;
#pragma unroll
      for (int r = 0; r < 3; ++r)
#pragma unroll
        for (int dx = 0; dx < 3; ++dx)
          a = fmaf(xv[r][dx], wj[r * 3 + dx], a);
      acc[jj] += a;
    }
  }

  __shared__ float red[4][4][64];
#pragma unroll
  for (int jj = 0; jj < 4; ++jj) red[cs][jj][w] = acc[jj];
  __syncthreads();

  int jj = t >> 6;
  int j = jq * 4 + jj;
  if (j < 27) {
    float s = red[0][jj][w] + red[1][jj][w] + red[2][jj][w] + red[3][jj][w] + b_om[j];
    float* pyA = pypxmk;
    float* pxA = pypxmk + 147456;
    float* mkA = pypxmk + 294912;
    if (j < 18) {
      int k = j >> 1;
      int off = (b * 9 + k) * HW + h * 64 + w;
      if ((j & 1) == 0)
        pyA[off] = (float)(h - 1 + k / 3) + s;   // absolute sample y
      else
        pxA[off] = (float)(w - 1 + k % 3) + s;   // absolute sample x
    } else {
      int k = j - 18;
      mkA[(b * 9 + k) * HW + h * 64 + w] = 1.f / (1.f + __expf(-s));
    }
  }
}

// ---------------- K2: bilinear gather -> cols bf16 [b*hw][k*256+c] ----------------
// block = (b, h, kt) with kt in 0..2 covering k = 3*kt..3*kt+2.
// Lanes sweep w (coalesced x gathers); LDS tile transposes to c-contiguous writes.
__global__ void k2_cols(const float* __restrict__ x, const float* __restrict__ pypxmk,
                        uint16_t* __restrict__ cols) {
  int bx = blockIdx.x;
  int kt = bx % 3;
  int h = (bx / 3) % 64;
  int b = bx / (3 * 64);
  int t = threadIdx.x;
  int w = t & 63;
  int g = t >> 6;

  const float* pyA = pypxmk;
  const float* pxA = pypxmk + 147456;
  const float* mkA = pypxmk + 294912;

  float wgt[3][4];
  int idx4[3][4];
#pragma unroll
  for (int kk = 0; kk < 3; ++kk) {
    int k = kt * 3 + kk;
    int poff = (b * 9 + k) * HW + h * 64 + w;
    float py = pyA[poff];
    float px = pxA[poff];
    float mk = mkA[poff];
    float fy0 = floorf(py), fx0 = floorf(px);
    float ly = py - fy0, lx = px - fx0;
    int y0 = (int)fy0, x0 = (int)fx0;
    int y1 = y0 + 1, x1 = x0 + 1;
    bool vy0 = ((unsigned)y0 < 64u), vy1 = ((unsigned)y1 < 64u);
    bool vx0 = ((unsigned)x0 < 64u), vx1 = ((unsigned)x1 < 64u);
    wgt[kk][0] = (vy0 && vx0) ? (1.f - ly) * (1.f - lx) * mk : 0.f;
    wgt[kk][1] = (vy0 && vx1) ? (1.f - ly) * lx * mk : 0.f;
    wgt[kk][2] = (vy1 && vx0) ? ly * (1.f - lx) * mk : 0.f;
    wgt[kk][3] = (vy1 && vx1) ? ly * lx * mk : 0.f;
    int cy0 = min(max(y0, 0), 63), cy1 = min(max(y1, 0), 63);
    int cx0 = min(max(x0, 0), 63), cx1 = min(max(x1, 0), 63);
    idx4[kk][0] = cy0 * 64 + cx0;
    idx4[kk][1] = cy0 * 64 + cx1;
    idx4[kk][2] = cy1 * 64 + cx0;
    idx4[kk][3] = cy1 * 64 + cx1;
  }

  __shared__ __align__(16) uint16_t tile[64 * 98];  // [w][kk(3)*32 + c32], stride 98 (odd dwords)
  const float* xb = x + b * C_ * HW;

  for (int ch = 0; ch < 8; ++ch) {  // c-chunks of 32
    int c0 = ch * 32 + g * 8;       // this thread's 8 c's
#pragma unroll
    for (int kk = 0; kk < 3; ++kk) {
#pragma unroll
      for (int i = 0; i < 8; i += 2) {
        float v2[2];
#pragma unroll
        for (int s = 0; s < 2; ++s) {
          const float* xc = xb + (c0 + i + s) * HW;
          v2[s] = wgt[kk][0] * xc[idx4[kk][0]] + wgt[kk][1] * xc[idx4[kk][1]] +
                  wgt[kk][2] * xc[idx4[kk][2]] + wgt[kk][3] * xc[idx4[kk][3]];
        }
        uint32_t pk = (uint32_t)f2bf(v2[0]) | ((uint32_t)f2bf(v2[1]) << 16);
        *(uint32_t*)&tile[w * 98 + kk * 32 + (g * 8 + i)] = pk;
      }
    }
    __syncthreads();
    // flush: 64w * 3k * 16 uints = 3072 uints, c-contiguous in global
#pragma unroll
    for (int i = 0; i < 12; ++i) {
      int u = t + i * 256;
      int wu = u / 48;
      int rem = u - wu * 48;
      int kku = rem >> 4;
      int cp = rem & 15;
      uint32_t val = *(const uint32_t*)&tile[wu * 98 + kku * 32 + cp * 2];
      int dst = (b * HW + h * 64 + wu) * CK + (kt * 3 + kku) * 256 + ch * 32 + cp * 2;
      *(uint32_t*)&cols[dst] = val;
    }
    __syncthreads();
  }
}

// ---------------- K3: GEMM out[b][o][hw] = wb[o][ck] . cols[n][ck] + bias ----------------
// M=256, N=16384, K=2304. 128x128 tile, BK=32, 4 waves (2x2), 16x16x32 bf16 MFMA.
__global__ void k3_gemm(const uint16_t* __restrict__ wb, const uint16_t* __restrict__ cols,
                        const float* __restrict__ bias, float* __restrict__ out) {
  int bx = blockIdx.x;
  int mt = bx & 1;
  int nt = bx >> 1;
  int o0 = mt * 128;
  int n0 = nt * 128;
  int t = threadIdx.x;
  int lane = t & 63;
  int wid = t >> 6;
  int wm = wid >> 1, wn = wid & 1;
  int lr = lane & 15, q = lane >> 4;

  __shared__ __align__(16) uint16_t As[128 * 32];
  __shared__ __align__(16) uint16_t Bs[128 * 32];

  f32x4 acc[4][4];
  const f32x4 zero = {0.f, 0.f, 0.f, 0.f};
#pragma unroll
  for (int i = 0; i < 4; ++i)
#pragma unroll
    for (int j = 0; j < 4; ++j) acc[i][j] = zero;

  int r0 = t >> 2;          // 0..63: tile row this thread stages
  int koff = (t & 3) * 8;   // 8 bf16 = 16B per lane
  const uint16_t* gA = wb + (o0 + r0) * CK + koff;
  const uint16_t* gB = cols + (n0 + r0) * CK + koff;

  for (int kt = 0; kt < 72; ++kt) {
    int k0 = kt * 32;
    __builtin_amdgcn_global_load_lds(
        (const __attribute__((address_space(1))) uint32_t*)(gA + k0),
        (__attribute__((address_space(3))) uint32_t*)&As[t * 8], 16, 0, 0);
    __builtin_amdgcn_global_load_lds(
        (const __attribute__((address_space(1))) uint32_t*)(gA + 64 * CK + k0),
        (__attribute__((address_space(3))) uint32_t*)&As[2048 + t * 8], 16, 0, 0);
    __builtin_amdgcn_global_load_lds(
        (const __attribute__((address_space(1))) uint32_t*)(gB + k0),
        (__attribute__((address_space(3))) uint32_t*)&Bs[t * 8], 16, 0, 0);
    __builtin_amdgcn_global_load_lds(
        (const __attribute__((address_space(1))) uint32_t*)(gB + 64 * CK + k0),
        (__attribute__((address_space(3))) uint32_t*)&Bs[2048 + t * 8], 16, 0, 0);
    __syncthreads();

    bf16x8 aF[4], bF[4];
#pragma unroll
    for (int i = 0; i < 4; ++i)
      aF[i] = *(const bf16x8*)&As[(wm * 64 + i * 16 + lr) * 32 + q * 8];
#pragma unroll
    for (int j = 0; j < 4; ++j)
      bF[j] = *(const bf16x8*)&Bs[(wn * 64 + j * 16 + lr) * 32 + q * 8];
#pragma unroll
    for (int i = 0; i < 4; ++i)
#pragma unroll
      for (int j = 0; j < 4; ++j)
        acc[i][j] = __builtin_amdgcn_mfma_f32_16x16x32_bf16(aF[i], bF[j], acc[i][j], 0, 0, 0);
    __syncthreads();
  }

  int bb = n0 >> 12;       // batch (BN=128 divides 4096)
  int hw0 = n0 & 4095;
#pragma unroll
  for (int i = 0; i < 4; ++i) {
#pragma unroll
    for (int r = 0; r < 4; ++r) {
      int o = o0 + wm * 64 + i * 16 + q * 4 + r;
      float bv = bias[o];
      float* orow = out + (bb * O_ + o) * HW + hw0;
#pragma unroll
      for (int j = 0; j < 4; ++j) orow[wn * 64 + j * 16 + lr] = acc[i][j][r] + bv;
    }
  }
}

extern "C" void kernel_launch(void* const* d_in, const int* in_sizes, int n_in,
                              void* d_out, int out_size, void* d_ws, size_t ws_size,
                              hipStream_t stream) {
  const float* x = (const float*)d_in[0];
  const float* w_om = (const float*)d_in[1];
  const float* b_om = (const float*)d_in[2];
  const float* weight = (const float*)d_in[3];
  const float* bias = (const float*)d_in[4];
  float* out = (float*)d_out;

  char* ws = (char*)d_ws;
  float* pypxmk = (float*)ws;                  // 442368 f32 = 1,769,472 B
  uint16_t* wb = (uint16_t*)(ws + 1769472);    // 589824 u16 = 1,179,648 B
  uint16_t* cols = (uint16_t*)(ws + 2949120);  // 37,748,736 u16 = 75,497,472 B

  hipLaunchKernelGGL(k0_wconv, dim3(2304), dim3(256), 0, stream, weight, wb);
  hipLaunchKernelGGL(k1_offconv, dim3(4 * 64 * 7), dim3(256), 0, stream, x, w_om, b_om, pypxmk);
  hipLaunchKernelGGL(k2_cols, dim3(4 * 64 * 3), dim3(256), 0, stream, x, pypxmk, cols);
  hipLaunchKernelGGL(k3_gemm, dim3(256), dim3(256), 0, stream, wb, cols, bias, out);
}

// Round 2
// 272.334 us; speedup vs baseline: 1.0033x; 1.0033x over previous
//
#include <hip/hip_runtime.h>
#include <stdint.h>

#define B_ 4
#define C_ 256
#define H_ 64
#define W_ 64
#define O_ 256
#define K_ 9
#define CK 2304     // K_*C_  (ck = k*256 + c, k-major)
#define HW 4096
#define NTOT 16384  // B_*HW

typedef __bf16 bf16x8 __attribute__((ext_vector_type(8)));
typedef float f32x4 __attribute__((ext_vector_type(4)));

__device__ __forceinline__ uint16_t f2bf(float f) {
  uint32_t u = __builtin_bit_cast(uint32_t, f);
  return (uint16_t)((u + 0x7FFFu + ((u >> 16) & 1u)) >> 16);
}

// ---------------- K0: weight fp32 [O][C][3][3] -> bf16 wb[O][k*256+c] ----------------
__global__ void k0_wconv(const float* __restrict__ weight, uint16_t* __restrict__ wb) {
  int idx = blockIdx.x * 256 + threadIdx.x;
  if (idx >= O_ * CK) return;
  int o = idx / CK;
  int rem = idx - o * CK;
  int k = rem >> 8;
  int c = rem & 255;
  wb[idx] = f2bf(weight[(o * C_ + c) * K_ + k]);
}

// ---------------- K1: offset conv (fp32) -> py/px/mask [b][k][h][w] ----------------
__global__ void k1_offconv(const float* __restrict__ x, const float* __restrict__ w_om,
                           const float* __restrict__ b_om, float* __restrict__ pypxmk) {
  int bx = blockIdx.x;
  int jq = bx % 7;
  int h = (bx / 7) % H_;
  int b = bx / (7 * H_);
  int t = threadIdx.x;
  int w = t & 63;
  int cs = __builtin_amdgcn_readfirstlane(t >> 6);

  float acc[4] = {0.f, 0.f, 0.f, 0.f};
  const float* xb = x + (b * C_) * HW;

  for (int ci = 0; ci < 64; ++ci) {
    int c = cs * 64 + ci;
    const float* xr = xb + c * HW;
    float xv[3][3];
#pragma unroll
    for (int r = 0; r < 3; ++r) {
      int y = h - 1 + r;
      bool yv = ((unsigned)y < 64u);
#pragma unroll
      for (int dx = 0; dx < 3; ++dx) {
        int xx = w - 1 + dx;
        bool v = yv && ((unsigned)xx < 64u);
        xv[r][dx] = v ? xr[y * 64 + xx] : 0.f;
      }
    }
    const float* wp = w_om + ((jq * 4) * C_ + c) * 9;
#pragma unroll
    for (int jj = 0; jj < 4; ++jj) {
      int j = jq * 4 + jj;
      int jeff = (j < 27) ? jj : 0;  // jq=6,jj=3 is dead; avoid OOB read
      const float* wj = wp + jeff * (C_ * 9);
      float a = 0.f;
#pragma unroll
      for (int r = 0; r < 3; ++r)
#pragma unroll
        for (int dx = 0; dx < 3; ++dx)
          a = fmaf(xv[r][dx], wj[r * 3 + dx], a);
      acc[jj] += a;
    }
  }

  __shared__ float red[4][4][64];
#pragma unroll
  for (int jj = 0; jj < 4; ++jj) red[cs][jj][w] = acc[jj];
  __syncthreads();

  int jj = t >> 6;
  int j = jq * 4 + jj;
  if (j < 27) {
    float s = red[0][jj][w] + red[1][jj][w] + red[2][jj][w] + red[3][jj][w] + b_om[j];
    float* pyA = pypxmk;
    float* pxA = pypxmk + 147456;
    float* mkA = pypxmk + 294912;
    if (j < 18) {
      int k = j >> 1;
      int off = (b * 9 + k) * HW + h * 64 + w;
      if ((j & 1) == 0)
        pyA[off] = (float)(h - 1 + k / 3) + s;   // absolute sample y
      else
        pxA[off] = (float)(w - 1 + k % 3) + s;   // absolute sample x
    } else {
      int k = j - 18;
      mkA[(b * 9 + k) * HW + h * 64 + w] = 1.f / (1.f + __expf(-s));
    }
  }
}

// ---------------- K2: bilinear gather -> cols bf16 [b*hw][k*256+c] ----------------
// Grid = (b, h, cg): 2048 blocks, each handles ALL 9 k's for one 32-channel group.
// Lanes sweep w (coalesced gathers, L1-hot 3x3 neighborhood reused across all 9 k).
// One LDS tile [64 w][288 +2 pad bf16] (stride 145 dwords, odd -> conflict-free),
// single barrier, then c-contiguous flush.
__global__ void k2_cols(const float* __restrict__ x, const float* __restrict__ pypxmk,
                        uint16_t* __restrict__ cols) {
  int bx = blockIdx.x;
  int cg = bx & 7;
  int h = (bx >> 3) & 63;
  int b = bx >> 9;
  int t = threadIdx.x;
  int w = t & 63;
  int g = t >> 6;

  const float* pyA = pypxmk;
  const float* pxA = pypxmk + 147456;
  const float* mkA = pypxmk + 294912;

  __shared__ uint16_t tile[64 * 290];  // 37,120 B
  const float* xb = x + b * C_ * HW;
  int cbase = cg * 32 + g * 8;

#pragma unroll
  for (int k = 0; k < 9; ++k) {
    int poff = (b * 9 + k) * HW + h * 64 + w;
    float py = pyA[poff];
    float px = pxA[poff];
    float mk = mkA[poff];
    float fy0 = floorf(py), fx0 = floorf(px);
    float ly = py - fy0, lx = px - fx0;
    int y0 = (int)fy0, x0 = (int)fx0;
    int y1 = y0 + 1, x1 = x0 + 1;
    bool vy0 = ((unsigned)y0 < 64u), vy1 = ((unsigned)y1 < 64u);
    bool vx0 = ((unsigned)x0 < 64u), vx1 = ((unsigned)x1 < 64u);
    float wgt[4];
    int idx[4];
    wgt[0] = (vy0 && vx0) ? (1.f - ly) * (1.f - lx) * mk : 0.f;
    wgt[1] = (vy0 && vx1) ? (1.f - ly) * lx * mk : 0.f;
    wgt[2] = (vy1 && vx0) ? ly * (1.f - lx) * mk : 0.f;
    wgt[3] = (vy1 && vx1) ? ly * lx * mk : 0.f;
    int cy0 = min(max(y0, 0), 63), cy1 = min(max(y1, 0), 63);
    int cx0 = min(max(x0, 0), 63), cx1 = min(max(x1, 0), 63);
    idx[0] = cy0 * 64 + cx0;
    idx[1] = cy0 * 64 + cx1;
    idx[2] = cy1 * 64 + cx0;
    idx[3] = cy1 * 64 + cx1;

    // issue all 32 gathers for this k up front (MLP), then interpolate
    float v[8][4];
#pragma unroll
    for (int i = 0; i < 8; ++i) {
      const float* xc = xb + (cbase + i) * HW;
#pragma unroll
      for (int j = 0; j < 4; ++j) v[i][j] = xc[idx[j]];
    }
#pragma unroll
    for (int i = 0; i < 8; i += 2) {
      float r0 = wgt[0] * v[i][0] + wgt[1] * v[i][1] + wgt[2] * v[i][2] + wgt[3] * v[i][3];
      float r1 = wgt[0] * v[i + 1][0] + wgt[1] * v[i + 1][1] + wgt[2] * v[i + 1][2] +
                 wgt[3] * v[i + 1][3];
      uint32_t pk = (uint32_t)f2bf(r0) | ((uint32_t)f2bf(r1) << 16);
      *(uint32_t*)&tile[w * 290 + k * 32 + g * 8 + i] = pk;
    }
  }
  __syncthreads();

  // flush: 64 rows x 144 dwords; u consecutive across lanes -> conflict-free LDS
  // reads and ~64B-granular coalesced global stores.
#pragma unroll
  for (int it = 0; it < 36; ++it) {
    int u = t + it * 256;
    int wu = u / 144;
    int rem = u - wu * 144;        // dword col: rem = k*16 + cd, cd in 0..15
    int k = rem >> 4;
    int cd = rem & 15;
    uint32_t val = *(const uint32_t*)&tile[wu * 290 + rem * 2];
    int n = b * HW + h * 64 + wu;
    int dst = n * CK + k * 256 + cg * 32 + cd * 2;
    *(uint32_t*)&cols[dst] = val;
  }
}

// ---------------- K3: GEMM dst[b][o][hw] (+)= wb[o][ck] . cols[n][ck] ----------------
// M=256, N=16384. 128x128 tile, BK=32, 4 waves (2x2), 16x16x32 bf16 MFMA.
// Split-K capable: grid = 256 * nsplit; block bx>>8 selects K-range and partial dst.
__global__ void k3_gemm(const uint16_t* __restrict__ wb, const uint16_t* __restrict__ cols,
                        const float* __restrict__ bias, float* __restrict__ dst,
                        int ktn, int withBias) {
  int bx = blockIdx.x;
  int ks = bx >> 8;
  int bxx = bx & 255;
  int mt = bxx & 1;
  int nt = bxx >> 1;
  int o0 = mt * 128;
  int n0 = nt * 128;
  int t = threadIdx.x;
  int lane = t & 63;
  int wid = t >> 6;
  int wm = wid >> 1, wn = wid & 1;
  int lr = lane & 15, q = lane >> 4;

  __shared__ __align__(16) uint16_t As[128 * 32];
  __shared__ __align__(16) uint16_t Bs[128 * 32];

  f32x4 acc[4][4];
  const f32x4 zero = {0.f, 0.f, 0.f, 0.f};
#pragma unroll
  for (int i = 0; i < 4; ++i)
#pragma unroll
    for (int j = 0; j < 4; ++j) acc[i][j] = zero;

  int r0 = t >> 2;          // 0..63: tile row this thread stages
  int koff = (t & 3) * 8;   // 8 bf16 = 16B per lane
  int kb = ks * ktn * 32;
  const uint16_t* gA = wb + (o0 + r0) * CK + kb + koff;
  const uint16_t* gB = cols + (n0 + r0) * CK + kb + koff;

  for (int kt = 0; kt < ktn; ++kt) {
    int k0 = kt * 32;
    __builtin_amdgcn_global_load_lds(
        (const __attribute__((address_space(1))) uint32_t*)(gA + k0),
        (__attribute__((address_space(3))) uint32_t*)&As[t * 8], 16, 0, 0);
    __builtin_amdgcn_global_load_lds(
        (const __attribute__((address_space(1))) uint32_t*)(gA + 64 * CK + k0),
        (__attribute__((address_space(3))) uint32_t*)&As[2048 + t * 8], 16, 0, 0);
    __builtin_amdgcn_global_load_lds(
        (const __attribute__((address_space(1))) uint32_t*)(gB + k0),
        (__attribute__((address_space(3))) uint32_t*)&Bs[t * 8], 16, 0, 0);
    __builtin_amdgcn_global_load_lds(
        (const __attribute__((address_space(1))) uint32_t*)(gB + 64 * CK + k0),
        (__attribute__((address_space(3))) uint32_t*)&Bs[2048 + t * 8], 16, 0, 0);
    __syncthreads();

    bf16x8 aF[4], bF[4];
#pragma unroll
    for (int i = 0; i < 4; ++i)
      aF[i] = *(const bf16x8*)&As[(wm * 64 + i * 16 + lr) * 32 + q * 8];
#pragma unroll
    for (int j = 0; j < 4; ++j)
      bF[j] = *(const bf16x8*)&Bs[(wn * 64 + j * 16 + lr) * 32 + q * 8];
#pragma unroll
    for (int i = 0; i < 4; ++i)
#pragma unroll
      for (int j = 0; j < 4; ++j)
        acc[i][j] = __builtin_amdgcn_mfma_f32_16x16x32_bf16(aF[i], bF[j], acc[i][j], 0, 0, 0);
    __syncthreads();
  }

  float* base = dst + ks * (O_ * NTOT);
  int bb = n0 >> 12;       // batch (BN=128 divides 4096)
  int hw0 = n0 & 4095;
#pragma unroll
  for (int i = 0; i < 4; ++i) {
#pragma unroll
    for (int r = 0; r < 4; ++r) {
      int o = o0 + wm * 64 + i * 16 + q * 4 + r;
      float bv = withBias ? bias[o] : 0.f;
      float* orow = base + (bb * O_ + o) * HW + hw0;
#pragma unroll
      for (int j = 0; j < 4; ++j) orow[wn * 64 + j * 16 + lr] = acc[i][j][r] + bv;
    }
  }
}

// ---------------- K4: reduce 3 split-K partials + bias -> out ----------------
__global__ void k4_reduce(const float* __restrict__ part, const float* __restrict__ bias,
                          float* __restrict__ out) {
  int i4 = blockIdx.x * 256 + threadIdx.x;  // float4 index, total 1048576
  const f32x4* p0 = (const f32x4*)part;
  const f32x4* p1 = p0 + (O_ * NTOT / 4);
  const f32x4* p2 = p1 + (O_ * NTOT / 4);
  f32x4 a = p0[i4] + p1[i4] + p2[i4];
  int o = (i4 >> 10) & 255;  // 1024 float4 per o-row
  ((f32x4*)out)[i4] = a + bias[o];
}

extern "C" void kernel_launch(void* const* d_in, const int* in_sizes, int n_in,
                              void* d_out, int out_size, void* d_ws, size_t ws_size,
                              hipStream_t stream) {
  const float* x = (const float*)d_in[0];
  const float* w_om = (const float*)d_in[1];
  const float* b_om = (const float*)d_in[2];
  const float* weight = (const float*)d_in[3];
  const float* bias = (const float*)d_in[4];
  float* out = (float*)d_out;

  char* ws = (char*)d_ws;
  float* pypxmk = (float*)ws;                  // 442,368 f32 = 1,769,472 B
  uint16_t* wb = (uint16_t*)(ws + 1769472);    // 589,824 u16 = 1,179,648 B
  uint16_t* cols = (uint16_t*)(ws + 2949120);  // 37,748,736 u16 = 75,497,472 B
  float* part = (float*)(ws + 78446592);       // 3 x 16,777,216 B split-K partials

  hipLaunchKernelGGL(k0_wconv, dim3(2304), dim3(256), 0, stream, weight, wb);
  hipLaunchKernelGGL(k1_offconv, dim3(4 * 64 * 7), dim3(256), 0, stream, x, w_om, b_om, pypxmk);
  hipLaunchKernelGGL(k2_cols, dim3(4 * 64 * 8), dim3(256), 0, stream, x, pypxmk, cols);

  bool splitk = ws_size >= 128778240ull;
  if (splitk) {
    // 768 blocks = 3 blocks/CU (m97 sweet spot); bias applied in reduce
    hipLaunchKernelGGL(k3_gemm, dim3(768), dim3(256), 0, stream, wb, cols, bias, part, 24, 0);
    hipLaunchKernelGGL(k4_reduce, dim3(4096), dim3(256), 0, stream, part, bias, out);
  } else {
    hipLaunchKernelGGL(k3_gemm, dim3(256), dim3(256), 0, stream, wb, cols, bias, out, 72, 1);
  }
}